// Round 22
// baseline (1896.773 us; speedup 1.0000x reference)
//
#include <hip/hip_runtime.h>
#include <hip/hip_bf16.h>

#define GG 512
#define NMAX 256
#define EE 1024
#define HH 3
#define EMB 256
#define NEDGE 1280   // EE + NMAX
#define NEG 0.2f

typedef __attribute__((ext_vector_type(8))) short bf16x8;
typedef __attribute__((ext_vector_type(4))) float f32x4;
#define MFMA16(A,B,C) __builtin_amdgcn_mfma_f32_16x16x32_bf16((A),(B),(C),0,0,0)

__device__ inline void bsplit(float v, unsigned short& s0, unsigned short& s1,
                              unsigned short& s2) {
  __hip_bfloat16 b0 = __float2bfloat16(v);
  float r1 = v - __bfloat162float(b0);
  __hip_bfloat16 b1 = __float2bfloat16(r1);
  float r2 = r1 - __bfloat162float(b1);
  __hip_bfloat16 b2 = __float2bfloat16(r2);
  s0 = *(unsigned short*)&b0; s1 = *(unsigned short*)&b1; s2 = *(unsigned short*)&b2;
}

// ---------------- prep kernels (per layer, tiny, run once) ----------------
__global__ void k_prep_wa(const float* __restrict__ W, const float* __restrict__ asrc,
                          const float* __restrict__ adst, float* __restrict__ wa_s,
                          float* __restrict__ wa_d, int f) {
  int t = blockIdx.x * blockDim.x + threadIdx.x;
  int tot = HH * f;
  if (t >= 2 * tot) return;
  int which = t / tot;
  int r = t - which * tot;
  int hd = r / f, ff = r - hd * f;
  const float* a = which ? adst : asrc;
  float s = 0.f;
  for (int c = 0; c < EMB; ++c)
    s += a[hd * EMB + c] * W[(size_t)(hd * EMB + c) * f + ff];
  (which ? wa_d : wa_s)[r] = s;
}

// mcatP[KP][256], rows >= 3f zero-padded
__global__ void k_prep_mcatP(const float* __restrict__ W, const float* __restrict__ htw,
                             float* __restrict__ mcat, int f, int KP) {
  int t = blockIdx.x * blockDim.x + threadIdx.x;
  if (t >= KP * EMB) return;
  int row = t >> 8, j = t & 255;
  float s = 0.f;
  if (row < 3 * f) {
    int hd = row / f, ff = row - hd * f;
    for (int c = 0; c < EMB; ++c)
      s += htw[(size_t)j * (HH * EMB) + hd * EMB + c] * W[(size_t)(hd * EMB + c) * f + ff];
  }
  mcat[(size_t)row * EMB + j] = s;
}

// Bt planes: [256 cols][KP] bf16 3-way split of mcatP^T
__global__ void k_prep_bt3(const float* __restrict__ mcat, unsigned short* __restrict__ B0,
                           unsigned short* __restrict__ B1, unsigned short* __restrict__ B2,
                           int KP) {
  int t = blockIdx.x * blockDim.x + threadIdx.x;
  if (t >= 256 * KP) return;
  int n = t / KP, k = t - n * KP;
  float v = mcat[(size_t)k * 256 + n];
  unsigned short s0, s1, s2;
  bsplit(v, s0, s1, s2);
  B0[t] = s0; B1[t] = s1; B2[t] = s2;
}

__global__ void k_prep_bb(const float* __restrict__ b, const float* __restrict__ htw,
                          const float* __restrict__ htb, float* __restrict__ bb) {
  int j = threadIdx.x;
  float s = htb[j];
  for (int k = 0; k < HH * EMB; ++k) s += b[k] * htw[(size_t)j * (HH * EMB) + k];
  bb[j] = s;
}

// q~[r] = sum_c mcatP[r][c] * p[c]  (double), r < 3f
__global__ void k_prep_q(const float* __restrict__ mcat, const float* __restrict__ p,
                         double* __restrict__ qv, int f) {
  int r = blockIdx.x * blockDim.x + threadIdx.x;
  if (r >= 3 * f) return;
  double s = 0.0;
  for (int c = 0; c < EMB; ++c) s += (double)mcat[(size_t)r * EMB + c] * (double)p[c];
  qv[r] = s;
}

// sc2[0] = bb.p (double), sc2[1] = ||p|| (double)
__global__ void k_prep_sc(const float* __restrict__ p, const float* __restrict__ bb,
                          double* __restrict__ sc2) {
  __shared__ double sh[256], sh2[256];
  int t = threadIdx.x;
  double pv = (double)p[t];
  sh[t] = pv * pv;
  sh2[t] = (double)bb[t] * pv;
  __syncthreads();
  for (int s = 128; s > 0; s >>= 1) {
    if (t < s) { sh[t] += sh[t + s]; sh2[t] += sh2[t + s]; }
    __syncthreads();
  }
  if (t == 0) { sc2[0] = sh2[0]; sc2[1] = sqrt(sh[0]); }
}

// ------- fused per-graph kernel: attn coeffs -> logits -> CSR -> alpha -> topk/remap --
__global__ __launch_bounds__(256) void k_graph(
    const int* __restrict__ src_in, const int* __restrict__ dst_in, int first,
    int* __restrict__ es, int* __restrict__ ed, int* __restrict__ em,
    const float* __restrict__ xin, const float* __restrict__ wa_s,
    const float* __restrict__ wa_d, const double* __restrict__ qv,
    const double* __restrict__ sc2,
    float4* __restrict__ a4, int* __restrict__ coff, int* __restrict__ elist,
    int* __restrict__ sel, float* __restrict__ val, int n_in, int f, int kout) {
  __shared__ float lgs[NEDGE * 3];
  __shared__ unsigned short sdst[NEDGE], ssrc[NEDGE];
  __shared__ unsigned char sval[NEDGE];
  __shared__ float sas[256][3], sad[256][3];
  __shared__ double stdt[256][3];
  __shared__ int cnt2[256];
  __shared__ int scn[256];
  __shared__ int off[257];
  __shared__ int elist_s[NEDGE];
  __shared__ float sscore[256];
  __shared__ unsigned long long keys[256];
  __shared__ int inv[256];
  int g = blockIdx.x, tid = threadIdx.x;
  int etot = EE + n_in;
  cnt2[tid] = 0;
  // phase 0: per-node attention coeffs (f32) + score dots (double) into LDS
  if (tid < n_in) {
    const float* xr = xin + ((size_t)g * n_in + tid) * f;
    float s0 = 0, s1 = 0, s2 = 0, d0 = 0, d1 = 0, d2 = 0;
    double t0 = 0, t1 = 0, t2 = 0;
    if (f == 256) {
      const float4* xr4 = (const float4*)xr;
      for (int c4 = 0; c4 < 64; ++c4) {
        float4 xv = xr4[c4];
        int c = c4 << 2;
        s0 += xv.x * wa_s[c] + xv.y * wa_s[c + 1] + xv.z * wa_s[c + 2] + xv.w * wa_s[c + 3];
        s1 += xv.x * wa_s[256 + c] + xv.y * wa_s[256 + c + 1] + xv.z * wa_s[256 + c + 2] + xv.w * wa_s[256 + c + 3];
        s2 += xv.x * wa_s[512 + c] + xv.y * wa_s[512 + c + 1] + xv.z * wa_s[512 + c + 2] + xv.w * wa_s[512 + c + 3];
        d0 += xv.x * wa_d[c] + xv.y * wa_d[c + 1] + xv.z * wa_d[c + 2] + xv.w * wa_d[c + 3];
        d1 += xv.x * wa_d[256 + c] + xv.y * wa_d[256 + c + 1] + xv.z * wa_d[256 + c + 2] + xv.w * wa_d[256 + c + 3];
        d2 += xv.x * wa_d[512 + c] + xv.y * wa_d[512 + c + 1] + xv.z * wa_d[512 + c + 2] + xv.w * wa_d[512 + c + 3];
        t0 += (double)xv.x * qv[c] + (double)xv.y * qv[c + 1] + (double)xv.z * qv[c + 2] + (double)xv.w * qv[c + 3];
        t1 += (double)xv.x * qv[256 + c] + (double)xv.y * qv[256 + c + 1] + (double)xv.z * qv[256 + c + 2] + (double)xv.w * qv[256 + c + 3];
        t2 += (double)xv.x * qv[512 + c] + (double)xv.y * qv[512 + c + 1] + (double)xv.z * qv[512 + c + 2] + (double)xv.w * qv[512 + c + 3];
      }
    } else {
      for (int c = 0; c < f; ++c) {
        float xv = xr[c];
        s0 += xv * wa_s[c]; s1 += xv * wa_s[f + c]; s2 += xv * wa_s[2 * f + c];
        d0 += xv * wa_d[c]; d1 += xv * wa_d[f + c]; d2 += xv * wa_d[2 * f + c];
        double xd = (double)xv;
        t0 += xd * qv[c]; t1 += xd * qv[f + c]; t2 += xd * qv[2 * f + c];
      }
    }
    sas[tid][0] = s0; sas[tid][1] = s1; sas[tid][2] = s2;
    sad[tid][0] = d0; sad[tid][1] = d1; sad[tid][2] = d2;
    stdt[tid][0] = t0; stdt[tid][1] = t1; stdt[tid][2] = t2;
  }
  __syncthreads();
  // phase 1: edge load + leaky-relu logits into LDS + per-dst counts
  for (int e = tid; e < etot; e += 256) {
    int s, d, v;
    if (e < EE) {
      if (first) { s = src_in[g * EE + e]; d = dst_in[g * EE + e]; v = 1; }
      else { s = es[g * EE + e]; d = ed[g * EE + e]; v = em[g * EE + e]; }
    } else { s = d = e - EE; v = 1; }
    sdst[e] = (unsigned short)d; ssrc[e] = (unsigned short)s; sval[e] = (unsigned char)v;
    if (v) {
#pragma unroll
      for (int h = 0; h < HH; ++h) {
        float lv = sas[s][h] + sad[d][h];
        lgs[e * 3 + h] = lv > 0.f ? lv : NEG * lv;
      }
      atomicAdd(&cnt2[d], 1);
    }
  }
  __syncthreads();
  // phase 2: parallel inclusive scan (Hillis-Steele) -> exclusive offsets
  scn[tid] = cnt2[tid];
  __syncthreads();
  for (int d = 1; d < 256; d <<= 1) {
    int t = (tid >= d) ? scn[tid - d] : 0;
    __syncthreads();
    scn[tid] += t;
    __syncthreads();
  }
  off[tid + 1] = scn[tid];
  if (tid == 0) off[0] = 0;
  __syncthreads();
  for (int i = tid; i <= n_in; i += 256) coff[g * 257 + i] = off[i];
  cnt2[tid] = 0;
  __syncthreads();
  // phase 3: CSR fill via atomic scatter, then per-dst insertion sort (deterministic)
  for (int e = tid; e < etot; e += 256) {
    if (sval[e]) {
      int d = sdst[e];
      int pos = atomicAdd(&cnt2[d], 1);
      elist_s[off[d] + pos] = e;
    }
  }
  __syncthreads();
  if (tid < n_in) {
    int o0 = off[tid], o1 = off[tid + 1];
    for (int i = o0 + 1; i < o1; ++i) {
      int key = elist_s[i];
      int j = i - 1;
      while (j >= o0 && elist_s[j] > key) { elist_s[j + 1] = elist_s[j]; --j; }
      elist_s[j + 1] = key;
    }
    for (int q = o0; q < o1; ++q) elist[g * NEDGE + q] = elist_s[q];
  }
  __syncthreads();
  // phase 4: per-dst softmax -> alpha (global a4) + score (double)
  float sc = -3e38f;
  if (tid < n_in) {
    int o0 = off[tid], o1 = off[tid + 1];
    float m0 = -1e30f, m1 = -1e30f, m2 = -1e30f;
    for (int q = o0; q < o1; ++q) {
      int e = elist_s[q];
      m0 = fmaxf(m0, lgs[e * 3 + 0]);
      m1 = fmaxf(m1, lgs[e * 3 + 1]);
      m2 = fmaxf(m2, lgs[e * 3 + 2]);
    }
    float d0 = 0, d1 = 0, d2 = 0;
    for (int q = o0; q < o1; ++q) {
      int e = elist_s[q];
      d0 += expf(lgs[e * 3 + 0] - m0);
      d1 += expf(lgs[e * 3 + 1] - m1);
      d2 += expf(lgs[e * 3 + 2] - m2);
    }
    float r0 = 1.f / d0, r1 = 1.f / d1, r2 = 1.f / d2;
    double s = 0.0;
    for (int q = o0; q < o1; ++q) {
      int e = elist_s[q];
      float w0 = expf(lgs[e * 3 + 0] - m0) * r0;
      float w1 = expf(lgs[e * 3 + 1] - m1) * r1;
      float w2 = expf(lgs[e * 3 + 2] - m2) * r2;
      int src = ssrc[e];
      float4 av; av.x = w0; av.y = w1; av.z = w2; av.w = __int_as_float(src);
      a4[(size_t)g * NEDGE + e] = av;
      s += (double)w0 * stdt[src][0] + (double)w1 * stdt[src][1] + (double)w2 * stdt[src][2];
    }
    sc = (float)tanh((s + sc2[0]) / sc2[1]);
  }
  sscore[tid] = sc;
  unsigned int u = __float_as_uint(sc);
  unsigned int ord = (u & 0x80000000u) ? ~u : (u | 0x80000000u);
  unsigned long long key = ((unsigned long long)(~ord) << 32) | (unsigned int)tid;
  if (tid >= n_in) key = 0xFFFFFFFF00000000ull | (unsigned int)tid;
  keys[tid] = key;
  __syncthreads();
  // phase 5: bitonic sort (value desc, index asc)
  for (int kk = 2; kk <= 256; kk <<= 1) {
    for (int j = kk >> 1; j > 0; j >>= 1) {
      int ixj = tid ^ j;
      if (ixj > tid) {
        unsigned long long a = keys[tid], b = keys[ixj];
        bool up = ((tid & kk) == 0);
        if (up ? (a > b) : (a < b)) { keys[tid] = b; keys[ixj] = a; }
      }
      __syncthreads();
    }
  }
  inv[tid] = -1;
  __syncthreads();
  if (tid < kout) {
    int pi = (int)(keys[tid] & 0xFFFFu);
    inv[pi] = tid;
    sel[g * 256 + tid] = pi;
    val[g * 256 + tid] = sscore[pi];
  }
  __syncthreads();
  // phase 6: edge remap (from LDS copies)
  for (int e = tid; e < EE; e += 256) {
    int s = ssrc[e], d = sdst[e], m = sval[e];
    int ns = inv[s], nd = inv[d];
    int nm = (m && ns >= 0 && nd >= 0) ? 1 : 0;
    es[g * EE + e] = ns < 0 ? 0 : ns;
    ed[g * EE + e] = nd < 0 ? 0 : nd;
    em[g * EE + e] = nm;
  }
}

// ------- gather for SELECTED rows only -> 3-way split bf16 planes [row][KP] ----------
template<bool F256>
__global__ __launch_bounds__(256) void k_gather_sel(
    const float* __restrict__ xin, const float4* __restrict__ a4,
    const int* __restrict__ coff, const int* __restrict__ elist,
    const int* __restrict__ sel,
    unsigned short* __restrict__ A0, unsigned short* __restrict__ A1,
    unsigned short* __restrict__ A2,
    int gc, int n_in, int n_out, int f, int KP) {
  int wid = (blockIdx.x * blockDim.x + threadIdx.x) >> 6;
  int lane = threadIdx.x & 63;
  if (wid >= gc * n_out) return;
  int g = wid / n_out, j = wid - g * n_out;
  int pi = sel[(g << 8) + j];
  int o0 = coff[g * 257 + pi], o1 = coff[g * 257 + pi + 1];
  const float* xg = xin + (size_t)g * n_in * f;
  size_t rb = ((size_t)g * n_out + j) * (size_t)KP;
  if (F256) {
    float4 acc0 = make_float4(0, 0, 0, 0);
    float4 acc1 = make_float4(0, 0, 0, 0);
    float4 acc2 = make_float4(0, 0, 0, 0);
    for (int t = o0; t < o1; ++t) {
      int e = elist[g * NEDGE + t];
      float4 a = a4[(size_t)g * NEDGE + e];
      int src = __float_as_int(a.w);
      float4 xv = ((const float4*)(xg + (size_t)src * 256))[lane];
      acc0.x += a.x * xv.x; acc0.y += a.x * xv.y; acc0.z += a.x * xv.z; acc0.w += a.x * xv.w;
      acc1.x += a.y * xv.x; acc1.y += a.y * xv.y; acc1.z += a.y * xv.z; acc1.w += a.y * xv.w;
      acc2.x += a.z * xv.x; acc2.y += a.z * xv.y; acc2.z += a.z * xv.z; acc2.w += a.z * xv.w;
    }
    float4 accs[3] = {acc0, acc1, acc2};
#pragma unroll
    for (int h = 0; h < 3; ++h) {
      size_t idx = rb + (size_t)h * 256 + lane * 4;
      ushort4 u0, u1, u2;
      bsplit(accs[h].x, u0.x, u1.x, u2.x);
      bsplit(accs[h].y, u0.y, u1.y, u2.y);
      bsplit(accs[h].z, u0.z, u1.z, u2.z);
      bsplit(accs[h].w, u0.w, u1.w, u2.w);
      *(ushort4*)&A0[idx] = u0;
      *(ushort4*)&A1[idx] = u1;
      *(ushort4*)&A2[idx] = u2;
    }
  } else {
    // f=30, KP=96: lane covers k = lane and lane+64 (<96)
    for (int kk = lane; kk < 96; kk += 64) {
      float v = 0.f;
      if (kk < 90) {
        int h = kk / 30, cc = kk - h * 30;
        for (int t = o0; t < o1; ++t) {
          int e = elist[g * NEDGE + t];
          float4 a = a4[(size_t)g * NEDGE + e];
          int src = __float_as_int(a.w);
          float al = (h == 0) ? a.x : ((h == 1) ? a.y : a.z);
          v += al * xg[(size_t)src * 30 + cc];
        }
      }
      unsigned short s0, s1, s2;
      bsplit(v, s0, s1, s2);
      A0[rb + kk] = s0; A1[rb + kk] = s1; A2[rb + kk] = s2;
    }
  }
}

// ------- MFMA split-bf16 GEMM, BK=32 (layer 0, KP=96) — r14 measured config -------
__global__ __launch_bounds__(256) void k_mgemm(
    const unsigned short* __restrict__ A0, const unsigned short* __restrict__ A1,
    const unsigned short* __restrict__ A2,
    const unsigned short* __restrict__ B0, const unsigned short* __restrict__ B1,
    const unsigned short* __restrict__ B2,
    const float* __restrict__ bias, const float* __restrict__ val,
    float* __restrict__ xout, int Mrows, int KP, int n_out, int nbx) {
  __shared__ unsigned short As[3][64 * 32];
  __shared__ unsigned short Bs[3][64 * 32];
  int tid = threadIdx.x;
  int jj = blockIdx.x & 31;
  int rr0 = (blockIdx.x >> 5) * 8 + (jj & 7);
  int cc0 = jj >> 3;                 // 0..3
  if (rr0 >= nbx) return;
  int row0 = rr0 * 64;
  int col0 = cc0 * 64;
  int lane = tid & 63, w = tid >> 6;
  int kg = lane >> 4, r16 = lane & 15;
  int wr = (w >> 1) * 32, wc = (w & 1) * 32;
  int sr = tid >> 2, sj = tid & 3;
  int sp = sj ^ ((sr >> 1) & 3);
  const unsigned short* Ap[3] = {A0, A1, A2};
  const unsigned short* Bp[3] = {B0, B1, B2};

  f32x4 acc[2][2];
#pragma unroll
  for (int i = 0; i < 2; ++i)
#pragma unroll
    for (int j = 0; j < 2; ++j) acc[i][j] = (f32x4){0.f, 0.f, 0.f, 0.f};

  int nkt = KP >> 5;
  for (int kt = 0; kt < nkt; ++kt) {
    int k0 = kt << 5;
    int gra = row0 + sr;
    int grb = col0 + sr;
#pragma unroll
    for (int p = 0; p < 3; ++p) {
      uint4 va = make_uint4(0, 0, 0, 0);
      if (gra < Mrows) va = *(const uint4*)&Ap[p][(size_t)gra * KP + k0 + (sj << 3)];
      *(uint4*)&As[p][sr * 32 + (sp << 3)] = va;
      uint4 vb = *(const uint4*)&Bp[p][(size_t)grb * KP + k0 + (sj << 3)];
      *(uint4*)&Bs[p][sr * 32 + (sp << 3)] = vb;
    }
    __syncthreads();
    bf16x8 af[2][3], bf[2][3];
#pragma unroll
    for (int fm = 0; fm < 2; ++fm) {
      int row = wr + (fm << 4) + r16;
      int pk = kg ^ ((row >> 1) & 3);
#pragma unroll
      for (int p = 0; p < 3; ++p)
        af[fm][p] = *(const bf16x8*)&As[p][row * 32 + (pk << 3)];
    }
#pragma unroll
    for (int fn = 0; fn < 2; ++fn) {
      int col = wc + (fn << 4) + r16;
      int pk = kg ^ ((col >> 1) & 3);
#pragma unroll
      for (int p = 0; p < 3; ++p)
        bf[fn][p] = *(const bf16x8*)&Bs[p][col * 32 + (pk << 3)];
    }
#pragma unroll
    for (int fm = 0; fm < 2; ++fm)
#pragma unroll
      for (int fn = 0; fn < 2; ++fn) {
        f32x4 c = acc[fm][fn];
        c = MFMA16(af[fm][0], bf[fn][0], c);
        c = MFMA16(af[fm][0], bf[fn][1], c);
        c = MFMA16(af[fm][1], bf[fn][0], c);
        c = MFMA16(af[fm][0], bf[fn][2], c);
        c = MFMA16(af[fm][2], bf[fn][0], c);
        c = MFMA16(af[fm][1], bf[fn][1], c);
        acc[fm][fn] = c;
      }
    __syncthreads();
  }
#pragma unroll
  for (int fm = 0; fm < 2; ++fm)
#pragma unroll
    for (int fn = 0; fn < 2; ++fn) {
      int colg = col0 + wc + (fn << 4) + r16;
      float bi = bias[colg];
#pragma unroll
      for (int rr = 0; rr < 4; ++rr) {
        int rowg = row0 + wr + (fm << 4) + (kg << 2) + rr;
        if (rowg < Mrows) {
          int gg = rowg / n_out, j = rowg - gg * n_out;
          xout[((size_t)gg * n_out + j) * EMB + colg] =
              (acc[fm][fn][rr] + bi) * val[(gg << 8) + j];
        }
      }
    }
}

// ------- MFMA split-bf16 GEMM, BK=64 (layers 1-2, KP=768): halves the number of
// latency episodes (12 k-tiles vs 24; 12 global loads in flight per thread vs 6).
// Per-k-tile MFMA order identical to BK=32 -> bitwise-same accumulation (selection-safe).
// LDS 48KB -> 3 blocks/CU. Writes cover all 32 banks uniformly via p=j^(row&7);
// fragment reads spread 16 lanes over 8 chunk-quads -> 2-way (free).
__global__ __launch_bounds__(256) void k_mgemm64(
    const unsigned short* __restrict__ A0, const unsigned short* __restrict__ A1,
    const unsigned short* __restrict__ A2,
    const unsigned short* __restrict__ B0, const unsigned short* __restrict__ B1,
    const unsigned short* __restrict__ B2,
    const float* __restrict__ bias, const float* __restrict__ val,
    float* __restrict__ xout, int Mrows, int KP, int n_out, int nbx) {
  __shared__ unsigned short As[3][64 * 64];
  __shared__ unsigned short Bs[3][64 * 64];
  int tid = threadIdx.x;
  int jj = blockIdx.x & 31;
  int rr0 = (blockIdx.x >> 5) * 8 + (jj & 7);
  int cc0 = jj >> 3;                 // 0..3 col-blocks share bid%8 -> same XCD
  if (rr0 >= nbx) return;
  int row0 = rr0 * 64;
  int col0 = cc0 * 64;
  int lane = tid & 63, w = tid >> 6;
  int kg = lane >> 4, r16 = lane & 15;
  int wr = (w >> 1) * 32, wc = (w & 1) * 32;
  const unsigned short* Ap[3] = {A0, A1, A2};
  const unsigned short* Bp[3] = {B0, B1, B2};

  f32x4 acc[2][2];
#pragma unroll
  for (int i = 0; i < 2; ++i)
#pragma unroll
    for (int j = 0; j < 2; ++j) acc[i][j] = (f32x4){0.f, 0.f, 0.f, 0.f};

  int nkt = KP >> 6;   // 12 for KP=768
  for (int kt = 0; kt < nkt; ++kt) {
    int k0 = kt << 6;
#pragma unroll
    for (int s2 = 0; s2 < 2; ++s2) {
      int s = tid + (s2 << 8);
      int row = s >> 3, j = s & 7;
      int p = j ^ (row & 7);
      int gra = row0 + row;
      int grb = col0 + row;
#pragma unroll
      for (int pl = 0; pl < 3; ++pl) {
        uint4 va = make_uint4(0, 0, 0, 0);
        if (gra < Mrows) va = *(const uint4*)&Ap[pl][(size_t)gra * KP + k0 + (j << 3)];
        *(uint4*)&As[pl][row * 64 + (p << 3)] = va;
        uint4 vb = *(const uint4*)&Bp[pl][(size_t)grb * KP + k0 + (j << 3)];
        *(uint4*)&Bs[pl][row * 64 + (p << 3)] = vb;
      }
    }
    __syncthreads();
#pragma unroll
    for (int inner = 0; inner < 2; ++inner) {
      int cbase = (inner << 2) + kg;        // logical chunk 0..7 within tile
      bf16x8 af[2][3], bf[2][3];
#pragma unroll
      for (int fm = 0; fm < 2; ++fm) {
        int row = wr + (fm << 4) + r16;
        int pk = cbase ^ (row & 7);
#pragma unroll
        for (int pl = 0; pl < 3; ++pl)
          af[fm][pl] = *(const bf16x8*)&As[pl][row * 64 + (pk << 3)];
      }
#pragma unroll
      for (int fn = 0; fn < 2; ++fn) {
        int col = wc + (fn << 4) + r16;
        int pk = cbase ^ (col & 7);
#pragma unroll
        for (int pl = 0; pl < 3; ++pl)
          bf[fn][pl] = *(const bf16x8*)&Bs[pl][col * 64 + (pk << 3)];
      }
#pragma unroll
      for (int fm = 0; fm < 2; ++fm)
#pragma unroll
        for (int fn = 0; fn < 2; ++fn) {
          f32x4 c = acc[fm][fn];
          c = MFMA16(af[fm][0], bf[fn][0], c);
          c = MFMA16(af[fm][0], bf[fn][1], c);
          c = MFMA16(af[fm][1], bf[fn][0], c);
          c = MFMA16(af[fm][0], bf[fn][2], c);
          c = MFMA16(af[fm][2], bf[fn][0], c);
          c = MFMA16(af[fm][1], bf[fn][1], c);
          acc[fm][fn] = c;
        }
    }
    __syncthreads();
  }
#pragma unroll
  for (int fm = 0; fm < 2; ++fm)
#pragma unroll
    for (int fn = 0; fn < 2; ++fn) {
      int colg = col0 + wc + (fn << 4) + r16;
      float bi = bias[colg];
#pragma unroll
      for (int rr = 0; rr < 4; ++rr) {
        int rowg = row0 + wr + (fm << 4) + (kg << 2) + rr;
        if (rowg < Mrows) {
          int gg = rowg / n_out, j = rowg - gg * n_out;
          xout[((size_t)gg * n_out + j) * EMB + colg] =
              (acc[fm][fn][rr] + bi) * val[(gg << 8) + j];
        }
      }
    }
}

// ---------------- readout: z += [max ; mean] over pooled rows ----------------
__global__ void k_readout(const float* __restrict__ x, float* __restrict__ z,
                          int n_out, int g0) {
  int g = blockIdx.x, c = threadIdx.x;
  float mx = -3e38f, sm = 0.f;
  for (int j = 0; j < n_out; ++j) {
    float v = x[((size_t)g * n_out + j) * EMB + c];
    mx = fmaxf(mx, v);
    sm += v;
  }
  z[(size_t)(g0 + g) * 512 + c] += mx;
  z[(size_t)(g0 + g) * 512 + 256 + c] += sm / (float)n_out;
}

// ---------------- final MLP ----------------
__global__ void k_mlp(const float* __restrict__ z, const float* __restrict__ l1w,
                      const float* __restrict__ l1b, const float* __restrict__ l2w,
                      const float* __restrict__ l2b, float* __restrict__ out) {
  __shared__ float zs[512];
  __shared__ float h1[256];
  int g = blockIdx.x, tid = threadIdx.x;
  zs[tid] = z[(size_t)g * 512 + tid];
  zs[256 + tid] = z[(size_t)g * 512 + 256 + tid];
  __syncthreads();
  float s = l1b[tid];
  for (int c = 0; c < 512; ++c) s += zs[c] * l1w[(size_t)tid * 512 + c];
  h1[tid] = s > 0.f ? s : 0.f;
  __syncthreads();
  if (tid < 2) {
    float o = l2b[tid];
    for (int c = 0; c < 256; ++c) o += h1[c] * l2w[(size_t)tid * 256 + c];
    out[g * 2 + tid] = o;
  }
}

extern "C" void kernel_launch(void* const* d_in, const int* in_sizes, int n_in_cnt,
                              void* d_out, int out_size, void* d_ws, size_t ws_size,
                              hipStream_t stream) {
  (void)in_sizes; (void)n_in_cnt; (void)out_size;
  const float* x0 = (const float*)d_in[0];
  const int* e_src = (const int*)d_in[1];
  const int* e_dst = (const int*)d_in[2];
  struct LP { const float *W, *as, *ad, *b, *hw, *hb, *p; int f, nin, nout, KP; };
  LP L[3];
  for (int l = 0; l < 3; ++l) {
    int base = 3 + l * 7;
    L[l].W  = (const float*)d_in[base + 0];
    L[l].as = (const float*)d_in[base + 1];
    L[l].ad = (const float*)d_in[base + 2];
    L[l].b  = (const float*)d_in[base + 3];
    L[l].hw = (const float*)d_in[base + 4];
    L[l].hb = (const float*)d_in[base + 5];
    L[l].p  = (const float*)d_in[base + 6];
  }
  L[0].f = 30;  L[1].f = 256; L[2].f = 256;
  L[0].nin = 256; L[0].nout = 205; L[0].KP = 96;
  L[1].nin = 205; L[1].nout = 164; L[1].KP = 768;
  L[2].nin = 164; L[2].nout = 132; L[2].KP = 768;
  const float* l1w = (const float*)d_in[24];
  const float* l1b = (const float*)d_in[25];
  const float* l2w = (const float*)d_in[26];
  const float* l2b = (const float*)d_in[27];
  float* out = (float*)d_out;

  char* w = (char*)d_ws;
  char* wend = w + ws_size;
  auto alloc = [&](size_t bytes) {
    char* r = w; w += (bytes + 255) & ~(size_t)255; return r;
  };
  // ---- fixed buffers ----
  float*  z = (float*)alloc((size_t)GG * 512 * 4);
  float *wa_s[3], *wa_d[3], *mcatP[3], *bbv[3];
  unsigned short *bt0[3], *bt1[3], *bt2[3];
  double *qv[3], *sc2[3];
  for (int l = 0; l < 3; ++l) {
    int KP = (l == 0) ? 96 : 768;
    wa_s[l]  = (float*)alloc((size_t)HH * 256 * 4);
    wa_d[l]  = (float*)alloc((size_t)HH * 256 * 4);
    mcatP[l] = (float*)alloc((size_t)768 * EMB * 4);
    bbv[l]   = (float*)alloc((size_t)EMB * 4);
    bt0[l]   = (unsigned short*)alloc((size_t)256 * KP * 2);
    bt1[l]   = (unsigned short*)alloc((size_t)256 * KP * 2);
    bt2[l]   = (unsigned short*)alloc((size_t)256 * KP * 2);
    qv[l]    = (double*)alloc((size_t)768 * 8);
    sc2[l]   = (double*)alloc(256);
  }

  // ---- adaptive chunk size (uncapped; r20 showed chunking cost dominates) ----
  const size_t AMAX = (size_t)164 * 768;     // max agg elems/graph across layers
  const size_t APAD = (size_t)64 * 768;      // tail-block OOB slack (staging reads)
  size_t fixed_used = (size_t)(w - (char*)d_ws);
  size_t per_g = (size_t)205 * EMB * 4               // xbuf (in-place layer output)
               + AMAX * 2 * 3                        // agg planes (3x bf16)
               + (size_t)NEDGE * 16                  // a4
               + (size_t)EE * 4 * 3                  // es, ed, em
               + (size_t)257 * 4 + (size_t)NEDGE * 4 // coff, elist
               + (size_t)256 * 4 * 2                 // sel, val
               + 24 * 256;                           // align slop
  size_t avail = (ws_size > fixed_used + 1048576) ? (ws_size - fixed_used - 1048576) : 0;
  int Gc = (int)(avail / per_g);
  if (Gc > GG) Gc = GG;
  if (Gc < 1) Gc = 1;
  int nchunks = (GG + Gc - 1) / Gc;
  Gc = (GG + nchunks - 1) / nchunks;

  // ---- per-chunk buffers (capacity Gc) ----
  float*  xbuf = (float*)alloc((size_t)Gc * 205 * EMB * 4);
  unsigned short* AP0 = (unsigned short*)alloc(((size_t)Gc * AMAX + APAD) * 2);
  unsigned short* AP1 = (unsigned short*)alloc(((size_t)Gc * AMAX + APAD) * 2);
  unsigned short* AP2 = (unsigned short*)alloc(((size_t)Gc * AMAX + APAD) * 2);
  float4* a4   = (float4*)alloc((size_t)Gc * NEDGE * 16);
  int*    es   = (int*)alloc((size_t)Gc * EE * 4);
  int*    ed   = (int*)alloc((size_t)Gc * EE * 4);
  int*    em   = (int*)alloc((size_t)Gc * EE * 4);
  int*    coff = (int*)alloc((size_t)Gc * 257 * 4);
  int*    elist= (int*)alloc((size_t)Gc * NEDGE * 4);
  int*    sel  = (int*)alloc((size_t)Gc * 256 * 4);
  float*  val  = (float*)alloc((size_t)Gc * 256 * 4);
  if (w > wend) return;  // avoid OOB launches

  (void)hipMemsetAsync(z, 0, (size_t)GG * 512 * 4, stream);

  // ---- per-layer prep (once) ----
  for (int l = 0; l < 3; ++l) {
    int f = L[l].f, KP = L[l].KP;
    k_prep_wa<<<(2 * HH * f + 255) / 256, 256, 0, stream>>>(L[l].W, L[l].as, L[l].ad, wa_s[l], wa_d[l], f);
    k_prep_mcatP<<<(KP * EMB + 255) / 256, 256, 0, stream>>>(L[l].W, L[l].hw, mcatP[l], f, KP);
    k_prep_bt3<<<(256 * KP + 255) / 256, 256, 0, stream>>>(mcatP[l], bt0[l], bt1[l], bt2[l], KP);
    k_prep_bb<<<1, 256, 0, stream>>>(L[l].b, L[l].hw, L[l].hb, bbv[l]);
    k_prep_q<<<(3 * f + 255) / 256, 256, 0, stream>>>(mcatP[l], L[l].p, qv[l], f);
    k_prep_sc<<<1, 256, 0, stream>>>(L[l].p, bbv[l], sc2[l]);
  }

  // ---- chunked pipeline over graphs ----
  for (int g0 = 0; g0 < GG; g0 += Gc) {
    int gc = (GG - g0 < Gc) ? (GG - g0) : Gc;
    const float* xin = x0 + (size_t)g0 * 256 * 30;
    for (int l = 0; l < 3; ++l) {
      int f = L[l].f, nin = L[l].nin, nout = L[l].nout, KP = L[l].KP;
      k_graph<<<gc, 256, 0, stream>>>(e_src + (size_t)g0 * EE, e_dst + (size_t)g0 * EE,
                                      (l == 0) ? 1 : 0, es, ed, em,
                                      xin, wa_s[l], wa_d[l], qv[l], sc2[l],
                                      a4, coff, elist, sel, val, nin, f, nout);
      { int waves = gc * nout;
        if (f == 256)
          k_gather_sel<true><<<(waves * 64 + 255) / 256, 256, 0, stream>>>(
              xin, a4, coff, elist, sel, AP0, AP1, AP2, gc, nin, nout, f, KP);
        else
          k_gather_sel<false><<<(waves * 64 + 255) / 256, 256, 0, stream>>>(
              xin, a4, coff, elist, sel, AP0, AP1, AP2, gc, nin, nout, f, KP);
      }
      { int Mrows = gc * nout;
        int nbx = (Mrows + 63) / 64;
        int nblk = ((nbx + 7) / 8) * 32;
        if (KP == 768)
          k_mgemm64<<<nblk, 256, 0, stream>>>(AP0, AP1, AP2, bt0[l], bt1[l], bt2[l],
                                              bbv[l], val, xbuf, Mrows, KP, nout, nbx);
        else
          k_mgemm<<<nblk, 256, 0, stream>>>(AP0, AP1, AP2, bt0[l], bt1[l], bt2[l],
                                            bbv[l], val, xbuf, Mrows, KP, nout, nbx);
      }
      k_readout<<<gc, 256, 0, stream>>>(xbuf, z, nout, g0);
      xin = xbuf;
    }
  }
  k_mlp<<<GG, 256, 0, stream>>>(z, l1w, l1b, l2w, l2b, out);
}

// Round 23
// 1807.201 us; speedup vs baseline: 1.0496x; 1.0496x over previous
//
#include <hip/hip_runtime.h>
#include <hip/hip_bf16.h>

#define GG 512
#define NMAX 256
#define EE 1024
#define HH 3
#define EMB 256
#define NEDGE 1280   // EE + NMAX
#define NEG 0.2f

typedef __attribute__((ext_vector_type(8))) short bf16x8;
typedef __attribute__((ext_vector_type(4))) float f32x4;
#define MFMA16(A,B,C) __builtin_amdgcn_mfma_f32_16x16x32_bf16((A),(B),(C),0,0,0)

__device__ inline void bsplit(float v, unsigned short& s0, unsigned short& s1,
                              unsigned short& s2) {
  __hip_bfloat16 b0 = __float2bfloat16(v);
  float r1 = v - __bfloat162float(b0);
  __hip_bfloat16 b1 = __float2bfloat16(r1);
  float r2 = r1 - __bfloat162float(b1);
  __hip_bfloat16 b2 = __float2bfloat16(r2);
  s0 = *(unsigned short*)&b0; s1 = *(unsigned short*)&b1; s2 = *(unsigned short*)&b2;
}

// ---------------- prep kernels (per layer, tiny, run once) ----------------
__global__ void k_prep_wa(const float* __restrict__ W, const float* __restrict__ asrc,
                          const float* __restrict__ adst, float* __restrict__ wa_s,
                          float* __restrict__ wa_d, int f) {
  int t = blockIdx.x * blockDim.x + threadIdx.x;
  int tot = HH * f;
  if (t >= 2 * tot) return;
  int which = t / tot;
  int r = t - which * tot;
  int hd = r / f, ff = r - hd * f;
  const float* a = which ? adst : asrc;
  float s = 0.f;
  for (int c = 0; c < EMB; ++c)
    s += a[hd * EMB + c] * W[(size_t)(hd * EMB + c) * f + ff];
  (which ? wa_d : wa_s)[r] = s;
}

// mcatP[KP][256], rows >= 3f zero-padded
__global__ void k_prep_mcatP(const float* __restrict__ W, const float* __restrict__ htw,
                             float* __restrict__ mcat, int f, int KP) {
  int t = blockIdx.x * blockDim.x + threadIdx.x;
  if (t >= KP * EMB) return;
  int row = t >> 8, j = t & 255;
  float s = 0.f;
  if (row < 3 * f) {
    int hd = row / f, ff = row - hd * f;
    for (int c = 0; c < EMB; ++c)
      s += htw[(size_t)j * (HH * EMB) + hd * EMB + c] * W[(size_t)(hd * EMB + c) * f + ff];
  }
  mcat[(size_t)row * EMB + j] = s;
}

// Bt planes: [256 cols][KP] bf16 3-way split of mcatP^T
__global__ void k_prep_bt3(const float* __restrict__ mcat, unsigned short* __restrict__ B0,
                           unsigned short* __restrict__ B1, unsigned short* __restrict__ B2,
                           int KP) {
  int t = blockIdx.x * blockDim.x + threadIdx.x;
  if (t >= 256 * KP) return;
  int n = t / KP, k = t - n * KP;
  float v = mcat[(size_t)k * 256 + n];
  unsigned short s0, s1, s2;
  bsplit(v, s0, s1, s2);
  B0[t] = s0; B1[t] = s1; B2[t] = s2;
}

__global__ void k_prep_bb(const float* __restrict__ b, const float* __restrict__ htw,
                          const float* __restrict__ htb, float* __restrict__ bb) {
  int j = threadIdx.x;
  float s = htb[j];
  for (int k = 0; k < HH * EMB; ++k) s += b[k] * htw[(size_t)j * (HH * EMB) + k];
  bb[j] = s;
}

// q~[r] = sum_c mcatP[r][c] * p[c]  (double), r < 3f
__global__ void k_prep_q(const float* __restrict__ mcat, const float* __restrict__ p,
                         double* __restrict__ qv, int f) {
  int r = blockIdx.x * blockDim.x + threadIdx.x;
  if (r >= 3 * f) return;
  double s = 0.0;
  for (int c = 0; c < EMB; ++c) s += (double)mcat[(size_t)r * EMB + c] * (double)p[c];
  qv[r] = s;
}

// sc2[0] = bb.p (double), sc2[1] = ||p|| (double)
__global__ void k_prep_sc(const float* __restrict__ p, const float* __restrict__ bb,
                          double* __restrict__ sc2) {
  __shared__ double sh[256], sh2[256];
  int t = threadIdx.x;
  double pv = (double)p[t];
  sh[t] = pv * pv;
  sh2[t] = (double)bb[t] * pv;
  __syncthreads();
  for (int s = 128; s > 0; s >>= 1) {
    if (t < s) { sh[t] += sh[t + s]; sh2[t] += sh2[t + s]; }
    __syncthreads();
  }
  if (t == 0) { sc2[0] = sh2[0]; sc2[1] = sqrt(sh[0]); }
}

// ------- fused per-graph kernel: attn coeffs -> logits -> CSR -> alpha -> topk/remap --
__global__ __launch_bounds__(256) void k_graph(
    const int* __restrict__ src_in, const int* __restrict__ dst_in, int first,
    int* __restrict__ es, int* __restrict__ ed, int* __restrict__ em,
    const float* __restrict__ xin, const float* __restrict__ wa_s,
    const float* __restrict__ wa_d, const double* __restrict__ qv,
    const double* __restrict__ sc2,
    float4* __restrict__ a4, int* __restrict__ coff, int* __restrict__ elist,
    int* __restrict__ sel, float* __restrict__ val, int n_in, int f, int kout) {
  __shared__ float lgs[NEDGE * 3];
  __shared__ unsigned short sdst[NEDGE], ssrc[NEDGE];
  __shared__ unsigned char sval[NEDGE];
  __shared__ float sas[256][3], sad[256][3];
  __shared__ double stdt[256][3];
  __shared__ int cnt2[256];
  __shared__ int scn[256];
  __shared__ int off[257];
  __shared__ int elist_s[NEDGE];
  __shared__ float sscore[256];
  __shared__ unsigned long long keys[256];
  __shared__ int inv[256];
  int g = blockIdx.x, tid = threadIdx.x;
  int etot = EE + n_in;
  cnt2[tid] = 0;
  // phase 0: per-node attention coeffs (f32) + score dots (double) into LDS
  if (tid < n_in) {
    const float* xr = xin + ((size_t)g * n_in + tid) * f;
    float s0 = 0, s1 = 0, s2 = 0, d0 = 0, d1 = 0, d2 = 0;
    double t0 = 0, t1 = 0, t2 = 0;
    if (f == 256) {
      const float4* xr4 = (const float4*)xr;
      for (int c4 = 0; c4 < 64; ++c4) {
        float4 xv = xr4[c4];
        int c = c4 << 2;
        s0 += xv.x * wa_s[c] + xv.y * wa_s[c + 1] + xv.z * wa_s[c + 2] + xv.w * wa_s[c + 3];
        s1 += xv.x * wa_s[256 + c] + xv.y * wa_s[256 + c + 1] + xv.z * wa_s[256 + c + 2] + xv.w * wa_s[256 + c + 3];
        s2 += xv.x * wa_s[512 + c] + xv.y * wa_s[512 + c + 1] + xv.z * wa_s[512 + c + 2] + xv.w * wa_s[512 + c + 3];
        d0 += xv.x * wa_d[c] + xv.y * wa_d[c + 1] + xv.z * wa_d[c + 2] + xv.w * wa_d[c + 3];
        d1 += xv.x * wa_d[256 + c] + xv.y * wa_d[256 + c + 1] + xv.z * wa_d[256 + c + 2] + xv.w * wa_d[256 + c + 3];
        d2 += xv.x * wa_d[512 + c] + xv.y * wa_d[512 + c + 1] + xv.z * wa_d[512 + c + 2] + xv.w * wa_d[512 + c + 3];
        t0 += (double)xv.x * qv[c] + (double)xv.y * qv[c + 1] + (double)xv.z * qv[c + 2] + (double)xv.w * qv[c + 3];
        t1 += (double)xv.x * qv[256 + c] + (double)xv.y * qv[256 + c + 1] + (double)xv.z * qv[256 + c + 2] + (double)xv.w * qv[256 + c + 3];
        t2 += (double)xv.x * qv[512 + c] + (double)xv.y * qv[512 + c + 1] + (double)xv.z * qv[512 + c + 2] + (double)xv.w * qv[512 + c + 3];
      }
    } else {
      for (int c = 0; c < f; ++c) {
        float xv = xr[c];
        s0 += xv * wa_s[c]; s1 += xv * wa_s[f + c]; s2 += xv * wa_s[2 * f + c];
        d0 += xv * wa_d[c]; d1 += xv * wa_d[f + c]; d2 += xv * wa_d[2 * f + c];
        double xd = (double)xv;
        t0 += xd * qv[c]; t1 += xd * qv[f + c]; t2 += xd * qv[2 * f + c];
      }
    }
    sas[tid][0] = s0; sas[tid][1] = s1; sas[tid][2] = s2;
    sad[tid][0] = d0; sad[tid][1] = d1; sad[tid][2] = d2;
    stdt[tid][0] = t0; stdt[tid][1] = t1; stdt[tid][2] = t2;
  }
  __syncthreads();
  // phase 1: edge load + leaky-relu logits into LDS + per-dst counts
  for (int e = tid; e < etot; e += 256) {
    int s, d, v;
    if (e < EE) {
      if (first) { s = src_in[g * EE + e]; d = dst_in[g * EE + e]; v = 1; }
      else { s = es[g * EE + e]; d = ed[g * EE + e]; v = em[g * EE + e]; }
    } else { s = d = e - EE; v = 1; }
    sdst[e] = (unsigned short)d; ssrc[e] = (unsigned short)s; sval[e] = (unsigned char)v;
    if (v) {
#pragma unroll
      for (int h = 0; h < HH; ++h) {
        float lv = sas[s][h] + sad[d][h];
        lgs[e * 3 + h] = lv > 0.f ? lv : NEG * lv;
      }
      atomicAdd(&cnt2[d], 1);
    }
  }
  __syncthreads();
  // phase 2: parallel inclusive scan (Hillis-Steele) -> exclusive offsets
  scn[tid] = cnt2[tid];
  __syncthreads();
  for (int d = 1; d < 256; d <<= 1) {
    int t = (tid >= d) ? scn[tid - d] : 0;
    __syncthreads();
    scn[tid] += t;
    __syncthreads();
  }
  off[tid + 1] = scn[tid];
  if (tid == 0) off[0] = 0;
  __syncthreads();
  for (int i = tid; i <= n_in; i += 256) coff[g * 257 + i] = off[i];
  cnt2[tid] = 0;
  __syncthreads();
  // phase 3: CSR fill via atomic scatter, then per-dst insertion sort (deterministic)
  for (int e = tid; e < etot; e += 256) {
    if (sval[e]) {
      int d = sdst[e];
      int pos = atomicAdd(&cnt2[d], 1);
      elist_s[off[d] + pos] = e;
    }
  }
  __syncthreads();
  if (tid < n_in) {
    int o0 = off[tid], o1 = off[tid + 1];
    for (int i = o0 + 1; i < o1; ++i) {
      int key = elist_s[i];
      int j = i - 1;
      while (j >= o0 && elist_s[j] > key) { elist_s[j + 1] = elist_s[j]; --j; }
      elist_s[j + 1] = key;
    }
    for (int q = o0; q < o1; ++q) elist[g * NEDGE + q] = elist_s[q];
  }
  __syncthreads();
  // phase 4: per-dst softmax -> alpha (global a4) + score (double)
  float sc = -3e38f;
  if (tid < n_in) {
    int o0 = off[tid], o1 = off[tid + 1];
    float m0 = -1e30f, m1 = -1e30f, m2 = -1e30f;
    for (int q = o0; q < o1; ++q) {
      int e = elist_s[q];
      m0 = fmaxf(m0, lgs[e * 3 + 0]);
      m1 = fmaxf(m1, lgs[e * 3 + 1]);
      m2 = fmaxf(m2, lgs[e * 3 + 2]);
    }
    float d0 = 0, d1 = 0, d2 = 0;
    for (int q = o0; q < o1; ++q) {
      int e = elist_s[q];
      d0 += expf(lgs[e * 3 + 0] - m0);
      d1 += expf(lgs[e * 3 + 1] - m1);
      d2 += expf(lgs[e * 3 + 2] - m2);
    }
    float r0 = 1.f / d0, r1 = 1.f / d1, r2 = 1.f / d2;
    double s = 0.0;
    for (int q = o0; q < o1; ++q) {
      int e = elist_s[q];
      float w0 = expf(lgs[e * 3 + 0] - m0) * r0;
      float w1 = expf(lgs[e * 3 + 1] - m1) * r1;
      float w2 = expf(lgs[e * 3 + 2] - m2) * r2;
      int src = ssrc[e];
      float4 av; av.x = w0; av.y = w1; av.z = w2; av.w = __int_as_float(src);
      a4[(size_t)g * NEDGE + e] = av;
      s += (double)w0 * stdt[src][0] + (double)w1 * stdt[src][1] + (double)w2 * stdt[src][2];
    }
    sc = (float)tanh((s + sc2[0]) / sc2[1]);
  }
  sscore[tid] = sc;
  unsigned int u = __float_as_uint(sc);
  unsigned int ord = (u & 0x80000000u) ? ~u : (u | 0x80000000u);
  unsigned long long key = ((unsigned long long)(~ord) << 32) | (unsigned int)tid;
  if (tid >= n_in) key = 0xFFFFFFFF00000000ull | (unsigned int)tid;
  keys[tid] = key;
  __syncthreads();
  // phase 5: bitonic sort (value desc, index asc)
  for (int kk = 2; kk <= 256; kk <<= 1) {
    for (int j = kk >> 1; j > 0; j >>= 1) {
      int ixj = tid ^ j;
      if (ixj > tid) {
        unsigned long long a = keys[tid], b = keys[ixj];
        bool up = ((tid & kk) == 0);
        if (up ? (a > b) : (a < b)) { keys[tid] = b; keys[ixj] = a; }
      }
      __syncthreads();
    }
  }
  inv[tid] = -1;
  __syncthreads();
  if (tid < kout) {
    int pi = (int)(keys[tid] & 0xFFFFu);
    inv[pi] = tid;
    sel[g * 256 + tid] = pi;
    val[g * 256 + tid] = sscore[pi];
  }
  __syncthreads();
  // phase 6: edge remap (from LDS copies)
  for (int e = tid; e < EE; e += 256) {
    int s = ssrc[e], d = sdst[e], m = sval[e];
    int ns = inv[s], nd = inv[d];
    int nm = (m && ns >= 0 && nd >= 0) ? 1 : 0;
    es[g * EE + e] = ns < 0 ? 0 : ns;
    ed[g * EE + e] = nd < 0 ? 0 : nd;
    em[g * EE + e] = nm;
  }
}

// ------- gather for SELECTED rows only -> 3-way split bf16 planes [row][KP] ----------
template<bool F256>
__global__ __launch_bounds__(256) void k_gather_sel(
    const float* __restrict__ xin, const float4* __restrict__ a4,
    const int* __restrict__ coff, const int* __restrict__ elist,
    const int* __restrict__ sel,
    unsigned short* __restrict__ A0, unsigned short* __restrict__ A1,
    unsigned short* __restrict__ A2,
    int gc, int n_in, int n_out, int f, int KP) {
  int wid = (blockIdx.x * blockDim.x + threadIdx.x) >> 6;
  int lane = threadIdx.x & 63;
  if (wid >= gc * n_out) return;
  int g = wid / n_out, j = wid - g * n_out;
  int pi = sel[(g << 8) + j];
  int o0 = coff[g * 257 + pi], o1 = coff[g * 257 + pi + 1];
  const float* xg = xin + (size_t)g * n_in * f;
  size_t rb = ((size_t)g * n_out + j) * (size_t)KP;
  if (F256) {
    float4 acc0 = make_float4(0, 0, 0, 0);
    float4 acc1 = make_float4(0, 0, 0, 0);
    float4 acc2 = make_float4(0, 0, 0, 0);
    for (int t = o0; t < o1; ++t) {
      int e = elist[g * NEDGE + t];
      float4 a = a4[(size_t)g * NEDGE + e];
      int src = __float_as_int(a.w);
      float4 xv = ((const float4*)(xg + (size_t)src * 256))[lane];
      acc0.x += a.x * xv.x; acc0.y += a.x * xv.y; acc0.z += a.x * xv.z; acc0.w += a.x * xv.w;
      acc1.x += a.y * xv.x; acc1.y += a.y * xv.y; acc1.z += a.y * xv.z; acc1.w += a.y * xv.w;
      acc2.x += a.z * xv.x; acc2.y += a.z * xv.y; acc2.z += a.z * xv.z; acc2.w += a.z * xv.w;
    }
    float4 accs[3] = {acc0, acc1, acc2};
#pragma unroll
    for (int h = 0; h < 3; ++h) {
      size_t idx = rb + (size_t)h * 256 + lane * 4;
      ushort4 u0, u1, u2;
      bsplit(accs[h].x, u0.x, u1.x, u2.x);
      bsplit(accs[h].y, u0.y, u1.y, u2.y);
      bsplit(accs[h].z, u0.z, u1.z, u2.z);
      bsplit(accs[h].w, u0.w, u1.w, u2.w);
      *(ushort4*)&A0[idx] = u0;
      *(ushort4*)&A1[idx] = u1;
      *(ushort4*)&A2[idx] = u2;
    }
  } else {
    // f=30, KP=96: lane covers k = lane and lane+64 (<96)
    for (int kk = lane; kk < 96; kk += 64) {
      float v = 0.f;
      if (kk < 90) {
        int h = kk / 30, cc = kk - h * 30;
        for (int t = o0; t < o1; ++t) {
          int e = elist[g * NEDGE + t];
          float4 a = a4[(size_t)g * NEDGE + e];
          int src = __float_as_int(a.w);
          float al = (h == 0) ? a.x : ((h == 1) ? a.y : a.z);
          v += al * xg[(size_t)src * 30 + cc];
        }
      }
      unsigned short s0, s1, s2;
      bsplit(v, s0, s1, s2);
      A0[rb + kk] = s0; A1[rb + kk] = s1; A2[rb + kk] = s2;
    }
  }
}

// ------- MFMA split-bf16 GEMM: xout = (A @ Bt^T + bias) * val, 6-term expansion -------
// r14/r21 measured-best config: BM=64, BN=64 (4 col-blocks/panel share bid%8 -> same
// XCD L2), BK=32, 256 thr = 4 waves 2x2 (32x32 each), single-buffered 24KB LDS.
// XOR swizzle chunk^=((row>>1)&3) on both write & read -> 0 bank conflicts (measured).
__global__ __launch_bounds__(256) void k_mgemm(
    const unsigned short* __restrict__ A0, const unsigned short* __restrict__ A1,
    const unsigned short* __restrict__ A2,
    const unsigned short* __restrict__ B0, const unsigned short* __restrict__ B1,
    const unsigned short* __restrict__ B2,
    const float* __restrict__ bias, const float* __restrict__ val,
    float* __restrict__ xout, int Mrows, int KP, int n_out, int nbx) {
  __shared__ unsigned short As[3][64 * 32];
  __shared__ unsigned short Bs[3][64 * 32];
  int tid = threadIdx.x;
  int jj = blockIdx.x & 31;
  int rr0 = (blockIdx.x >> 5) * 8 + (jj & 7);
  int cc0 = jj >> 3;                 // 0..3
  if (rr0 >= nbx) return;
  int row0 = rr0 * 64;
  int col0 = cc0 * 64;
  int lane = tid & 63, w = tid >> 6;
  int kg = lane >> 4, r16 = lane & 15;
  int wr = (w >> 1) * 32, wc = (w & 1) * 32;
  int sr = tid >> 2, sj = tid & 3;               // stage: row, logical 16B chunk
  int sp = sj ^ ((sr >> 1) & 3);                 // physical chunk (XOR swizzle)
  const unsigned short* Ap[3] = {A0, A1, A2};
  const unsigned short* Bp[3] = {B0, B1, B2};

  f32x4 acc[2][2];
#pragma unroll
  for (int i = 0; i < 2; ++i)
#pragma unroll
    for (int j = 0; j < 2; ++j) acc[i][j] = (f32x4){0.f, 0.f, 0.f, 0.f};

  int nkt = KP >> 5;
  for (int kt = 0; kt < nkt; ++kt) {
    int k0 = kt << 5;
    int gra = row0 + sr;
    int grb = col0 + sr;
#pragma unroll
    for (int p = 0; p < 3; ++p) {
      uint4 va = make_uint4(0, 0, 0, 0);
      if (gra < Mrows) va = *(const uint4*)&Ap[p][(size_t)gra * KP + k0 + (sj << 3)];
      *(uint4*)&As[p][sr * 32 + (sp << 3)] = va;
      uint4 vb = *(const uint4*)&Bp[p][(size_t)grb * KP + k0 + (sj << 3)];
      *(uint4*)&Bs[p][sr * 32 + (sp << 3)] = vb;
    }
    __syncthreads();
    bf16x8 af[2][3], bf[2][3];
#pragma unroll
    for (int fm = 0; fm < 2; ++fm) {
      int row = wr + (fm << 4) + r16;
      int pk = kg ^ ((row >> 1) & 3);
#pragma unroll
      for (int p = 0; p < 3; ++p)
        af[fm][p] = *(const bf16x8*)&As[p][row * 32 + (pk << 3)];
    }
#pragma unroll
    for (int fn = 0; fn < 2; ++fn) {
      int col = wc + (fn << 4) + r16;
      int pk = kg ^ ((col >> 1) & 3);
#pragma unroll
      for (int p = 0; p < 3; ++p)
        bf[fn][p] = *(const bf16x8*)&Bs[p][col * 32 + (pk << 3)];
    }
#pragma unroll
    for (int fm = 0; fm < 2; ++fm)
#pragma unroll
      for (int fn = 0; fn < 2; ++fn) {
        f32x4 c = acc[fm][fn];
        c = MFMA16(af[fm][0], bf[fn][0], c);
        c = MFMA16(af[fm][0], bf[fn][1], c);
        c = MFMA16(af[fm][1], bf[fn][0], c);
        c = MFMA16(af[fm][0], bf[fn][2], c);
        c = MFMA16(af[fm][2], bf[fn][0], c);
        c = MFMA16(af[fm][1], bf[fn][1], c);
        acc[fm][fn] = c;
      }
    __syncthreads();
  }
  // epilogue: C row=(kg<<2)+rr, col=r16 per 16x16 frag
#pragma unroll
  for (int fm = 0; fm < 2; ++fm)
#pragma unroll
    for (int fn = 0; fn < 2; ++fn) {
      int colg = col0 + wc + (fn << 4) + r16;
      float bi = bias[colg];
#pragma unroll
      for (int rr = 0; rr < 4; ++rr) {
        int rowg = row0 + wr + (fm << 4) + (kg << 2) + rr;
        if (rowg < Mrows) {
          int gg = rowg / n_out, j = rowg - gg * n_out;
          xout[((size_t)gg * n_out + j) * EMB + colg] =
              (acc[fm][fn][rr] + bi) * val[(gg << 8) + j];
        }
      }
    }
}

// ---------------- readout: z += [max ; mean] over pooled rows ----------------
__global__ void k_readout(const float* __restrict__ x, float* __restrict__ z,
                          int n_out, int g0) {
  int g = blockIdx.x, c = threadIdx.x;
  float mx = -3e38f, sm = 0.f;
  for (int j = 0; j < n_out; ++j) {
    float v = x[((size_t)g * n_out + j) * EMB + c];
    mx = fmaxf(mx, v);
    sm += v;
  }
  z[(size_t)(g0 + g) * 512 + c] += mx;
  z[(size_t)(g0 + g) * 512 + 256 + c] += sm / (float)n_out;
}

// ---------------- final MLP ----------------
__global__ void k_mlp(const float* __restrict__ z, const float* __restrict__ l1w,
                      const float* __restrict__ l1b, const float* __restrict__ l2w,
                      const float* __restrict__ l2b, float* __restrict__ out) {
  __shared__ float zs[512];
  __shared__ float h1[256];
  int g = blockIdx.x, tid = threadIdx.x;
  zs[tid] = z[(size_t)g * 512 + tid];
  zs[256 + tid] = z[(size_t)g * 512 + 256 + tid];
  __syncthreads();
  float s = l1b[tid];
  for (int c = 0; c < 512; ++c) s += zs[c] * l1w[(size_t)tid * 512 + c];
  h1[tid] = s > 0.f ? s : 0.f;
  __syncthreads();
  if (tid < 2) {
    float o = l2b[tid];
    for (int c = 0; c < 256; ++c) o += h1[c] * l2w[(size_t)tid * 256 + c];
    out[g * 2 + tid] = o;
  }
}

extern "C" void kernel_launch(void* const* d_in, const int* in_sizes, int n_in_cnt,
                              void* d_out, int out_size, void* d_ws, size_t ws_size,
                              hipStream_t stream) {
  (void)in_sizes; (void)n_in_cnt; (void)out_size;
  const float* x0 = (const float*)d_in[0];
  const int* e_src = (const int*)d_in[1];
  const int* e_dst = (const int*)d_in[2];
  struct LP { const float *W, *as, *ad, *b, *hw, *hb, *p; int f, nin, nout, KP; };
  LP L[3];
  for (int l = 0; l < 3; ++l) {
    int base = 3 + l * 7;
    L[l].W  = (const float*)d_in[base + 0];
    L[l].as = (const float*)d_in[base + 1];
    L[l].ad = (const float*)d_in[base + 2];
    L[l].b  = (const float*)d_in[base + 3];
    L[l].hw = (const float*)d_in[base + 4];
    L[l].hb = (const float*)d_in[base + 5];
    L[l].p  = (const float*)d_in[base + 6];
  }
  L[0].f = 30;  L[1].f = 256; L[2].f = 256;
  L[0].nin = 256; L[0].nout = 205; L[0].KP = 96;
  L[1].nin = 205; L[1].nout = 164; L[1].KP = 768;
  L[2].nin = 164; L[2].nout = 132; L[2].KP = 768;
  const float* l1w = (const float*)d_in[24];
  const float* l1b = (const float*)d_in[25];
  const float* l2w = (const float*)d_in[26];
  const float* l2b = (const float*)d_in[27];
  float* out = (float*)d_out;

  char* w = (char*)d_ws;
  char* wend = w + ws_size;
  auto alloc = [&](size_t bytes) {
    char* r = w; w += (bytes + 255) & ~(size_t)255; return r;
  };
  // ---- fixed buffers ----
  float*  z = (float*)alloc((size_t)GG * 512 * 4);
  float *wa_s[3], *wa_d[3], *mcatP[3], *bbv[3];
  unsigned short *bt0[3], *bt1[3], *bt2[3];
  double *qv[3], *sc2[3];
  for (int l = 0; l < 3; ++l) {
    int KP = (l == 0) ? 96 : 768;
    wa_s[l]  = (float*)alloc((size_t)HH * 256 * 4);
    wa_d[l]  = (float*)alloc((size_t)HH * 256 * 4);
    mcatP[l] = (float*)alloc((size_t)768 * EMB * 4);
    bbv[l]   = (float*)alloc((size_t)EMB * 4);
    bt0[l]   = (unsigned short*)alloc((size_t)256 * KP * 2);
    bt1[l]   = (unsigned short*)alloc((size_t)256 * KP * 2);
    bt2[l]   = (unsigned short*)alloc((size_t)256 * KP * 2);
    qv[l]    = (double*)alloc((size_t)768 * 8);
    sc2[l]   = (double*)alloc(256);
  }

  // ---- adaptive chunk size (uncapped; r20 showed chunking cost dominates) ----
  const size_t AMAX = (size_t)164 * 768;     // max agg elems/graph across layers
  const size_t APAD = (size_t)64 * 768;      // tail-block OOB slack (staging reads)
  size_t fixed_used = (size_t)(w - (char*)d_ws);
  size_t per_g = (size_t)205 * EMB * 4               // xbuf (in-place layer output)
               + AMAX * 2 * 3                        // agg planes (3x bf16)
               + (size_t)NEDGE * 16                  // a4
               + (size_t)EE * 4 * 3                  // es, ed, em
               + (size_t)257 * 4 + (size_t)NEDGE * 4 // coff, elist
               + (size_t)256 * 4 * 2                 // sel, val
               + 24 * 256;                           // align slop
  size_t avail = (ws_size > fixed_used + 1048576) ? (ws_size - fixed_used - 1048576) : 0;
  int Gc = (int)(avail / per_g);
  if (Gc > GG) Gc = GG;
  if (Gc < 1) Gc = 1;
  int nchunks = (GG + Gc - 1) / Gc;
  Gc = (GG + nchunks - 1) / nchunks;

  // ---- per-chunk buffers (capacity Gc) ----
  float*  xbuf = (float*)alloc((size_t)Gc * 205 * EMB * 4);
  unsigned short* AP0 = (unsigned short*)alloc(((size_t)Gc * AMAX + APAD) * 2);
  unsigned short* AP1 = (unsigned short*)alloc(((size_t)Gc * AMAX + APAD) * 2);
  unsigned short* AP2 = (unsigned short*)alloc(((size_t)Gc * AMAX + APAD) * 2);
  float4* a4   = (float4*)alloc((size_t)Gc * NEDGE * 16);
  int*    es   = (int*)alloc((size_t)Gc * EE * 4);
  int*    ed   = (int*)alloc((size_t)Gc * EE * 4);
  int*    em   = (int*)alloc((size_t)Gc * EE * 4);
  int*    coff = (int*)alloc((size_t)Gc * 257 * 4);
  int*    elist= (int*)alloc((size_t)Gc * NEDGE * 4);
  int*    sel  = (int*)alloc((size_t)Gc * 256 * 4);
  float*  val  = (float*)alloc((size_t)Gc * 256 * 4);
  if (w > wend) return;  // avoid OOB launches

  (void)hipMemsetAsync(z, 0, (size_t)GG * 512 * 4, stream);

  // ---- per-layer prep (once) ----
  for (int l = 0; l < 3; ++l) {
    int f = L[l].f, KP = L[l].KP;
    k_prep_wa<<<(2 * HH * f + 255) / 256, 256, 0, stream>>>(L[l].W, L[l].as, L[l].ad, wa_s[l], wa_d[l], f);
    k_prep_mcatP<<<(KP * EMB + 255) / 256, 256, 0, stream>>>(L[l].W, L[l].hw, mcatP[l], f, KP);
    k_prep_bt3<<<(256 * KP + 255) / 256, 256, 0, stream>>>(mcatP[l], bt0[l], bt1[l], bt2[l], KP);
    k_prep_bb<<<1, 256, 0, stream>>>(L[l].b, L[l].hw, L[l].hb, bbv[l]);
    k_prep_q<<<(3 * f + 255) / 256, 256, 0, stream>>>(mcatP[l], L[l].p, qv[l], f);
    k_prep_sc<<<1, 256, 0, stream>>>(L[l].p, bbv[l], sc2[l]);
  }

  // ---- chunked pipeline over graphs ----
  for (int g0 = 0; g0 < GG; g0 += Gc) {
    int gc = (GG - g0 < Gc) ? (GG - g0) : Gc;
    const float* xin = x0 + (size_t)g0 * 256 * 30;
    for (int l = 0; l < 3; ++l) {
      int f = L[l].f, nin = L[l].nin, nout = L[l].nout, KP = L[l].KP;
      k_graph<<<gc, 256, 0, stream>>>(e_src + (size_t)g0 * EE, e_dst + (size_t)g0 * EE,
                                      (l == 0) ? 1 : 0, es, ed, em,
                                      xin, wa_s[l], wa_d[l], qv[l], sc2[l],
                                      a4, coff, elist, sel, val, nin, f, nout);
      { int waves = gc * nout;
        if (f == 256)
          k_gather_sel<true><<<(waves * 64 + 255) / 256, 256, 0, stream>>>(
              xin, a4, coff, elist, sel, AP0, AP1, AP2, gc, nin, nout, f, KP);
        else
          k_gather_sel<false><<<(waves * 64 + 255) / 256, 256, 0, stream>>>(
              xin, a4, coff, elist, sel, AP0, AP1, AP2, gc, nin, nout, f, KP);
      }
      { int Mrows = gc * nout;
        int nbx = (Mrows + 63) / 64;
        int nblk = ((nbx + 7) / 8) * 32;
        k_mgemm<<<nblk, 256, 0, stream>>>(AP0, AP1, AP2, bt0[l], bt1[l], bt2[l],
                                          bbv[l], val, xbuf, Mrows, KP, nout, nbx);
      }
      k_readout<<<gc, 256, 0, stream>>>(xbuf, z, nout, g0);
      xin = xbuf;
    }
  }
  k_mlp<<<GG, 256, 0, stream>>>(z, l1w, l1b, l2w, l2b, out);
}